// Round 3
// baseline (219.412 us; speedup 1.0000x reference)
//
#include <hip/hip_runtime.h>
#include <math.h>

// ---------------------------------------------------------------------------
// TitansMemoryModule fused update, MI355X (gfx950) — round 3
//   K2: retrieved = bf16(K) @ bf16(W)^T — reg-staged f32->bf16 conversion
//       fused (K1 eliminated), padded LDS (stride 72) kills read conflicts.
//       Writes k16 (each block its 32-row share), diff16, loss/colv partials.
//   K3: grad = diff^T @ k, split-K 32 chunks, 4-slab atomic grad accum,
//       fused colk column sums (vd0==0 blocks).
//   c1: all small reductions + gates (1 block).  c2-c4: momentum/weight.
// Output (flat f32): retrieved[16777216], loss, new_weight[262144],
//   new_momentum[262144], alpha, eta, theta
// ---------------------------------------------------------------------------

typedef __bf16 bf16x8 __attribute__((ext_vector_type(8)));
typedef float f32x4 __attribute__((ext_vector_type(4)));
typedef float float4_t __attribute__((ext_vector_type(4)));
typedef unsigned short ushort4_t __attribute__((ext_vector_type(4)));
typedef unsigned short ushort8_t __attribute__((ext_vector_type(8)));

#define OUT_LOSS   16777216
#define OUT_W      16777217
#define OUT_MOM    17039361
#define OUT_ALPHA  17301505

// ws layout (bytes), total ~68.6 MB
#define OFF_GRAD   0u           // grad_part [4][512][512] f32 = 4 MB  [memset 0]
#define OFF_CKP    4194304u     // colk_part [32][512] f32 = 64 KB   (from K3)
#define OFF_CVP    4259840u     // colv_part [256][512] f32 = 512 KB (from K2)
#define OFF_LOSSP  4784128u     // loss_part [1024] f32 (plain stores, from K2)
#define OFF_SCAL   4788224u     // scal[16]: 1=||m||^2 2=||w||^2 3=a 4=e 5=t
#define OFF_K16    4788288u     // 32 MB bf16 K
#define OFF_DIFF   38342720u    // 32 MB bf16 diff
#define OFF_MRAW   OFF_K16      // m_raw aliases k16 (dead after K3)
#define OFF_WRAW   (OFF_K16 + 1048576u)

__device__ __forceinline__ ushort4_t cvt4(float4_t v) {
  union { __bf16 b; unsigned short u; } c0, c1, c2, c3;
  c0.b = (__bf16)v.x; c1.b = (__bf16)v.y; c2.b = (__bf16)v.z; c3.b = (__bf16)v.w;
  ushort4_t h; h.x = c0.u; h.y = c1.u; h.z = c2.u; h.w = c3.u;
  return h;
}

__device__ __forceinline__ float bf2f(unsigned short u) {
  return __uint_as_float(((unsigned int)u) << 16);
}

// ---------------------------------------------------------------------------
// K2: retrieved = k @ W^T with fused f32->bf16 conversion.
// 128x128 tile, BK=64, 4 waves (2x2 of 64x64), mfma_f32_16x16x32_bf16.
// LDS stride 72 (144 B): 2-way banks on b128 reads = free; rows 16B-aligned.
// ---------------------------------------------------------------------------
__global__ __launch_bounds__(256) void k2_gemm(
    const float* __restrict__ Kp, const float* __restrict__ Wp,
    const float* __restrict__ Vp, float* __restrict__ outp,
    unsigned short* __restrict__ k16, unsigned short* __restrict__ diff16,
    float* __restrict__ colv_part, float* __restrict__ loss_part)
{
  __shared__ __align__(16) unsigned short As[128 * 72];
  __shared__ __align__(16) unsigned short Bs[128 * 72];
  __shared__ float redc[256];
  __shared__ float redl[4];

  const int t = threadIdx.x, lane = t & 63, wv = t >> 6;
  // XCD-grouped swizzle: the 4 vd-siblings of a rowtile share one XCD's L2.
  const int tile = (blockIdx.x & 7) * 128 + (blockIdx.x >> 3);
  const int rt = tile >> 2, vt = tile & 3;
  const int row0 = rt << 7, vd0 = vt << 7;

  f32x4 acc[4][4];
#pragma unroll
  for (int m = 0; m < 4; ++m)
#pragma unroll
    for (int n = 0; n < 4; ++n)
      acc[m][n] = (f32x4){0.f, 0.f, 0.f, 0.f};

  const int srow = t >> 4;          // 0..15
  const int scol = (t & 15) << 2;   // float4 col
  const int fr = lane & 15, fq = lane >> 4;
  const int wr = (wv >> 1) << 6, wc = (wv & 1) << 6;

  for (int kk0 = 0; kk0 < 512; kk0 += 64) {
#pragma unroll
    for (int p = 0; p < 8; ++p) {
      const int r = (p << 4) + srow;
      const size_t ga = (size_t)(row0 + r) * 512 + kk0 + scol;
      const float4_t av = *reinterpret_cast<const float4_t*>(&Kp[ga]);
      const ushort4_t ah = cvt4(av);
      *reinterpret_cast<ushort4_t*>(&As[r * 72 + scol]) = ah;
      if ((p >> 1) == vt)                     // this block's 32-row k16 share
        *reinterpret_cast<ushort4_t*>(&k16[ga]) = ah;
      const size_t gb = (size_t)(vd0 + r) * 512 + kk0 + scol;
      const float4_t bv = *reinterpret_cast<const float4_t*>(&Wp[gb]);
      *reinterpret_cast<ushort4_t*>(&Bs[r * 72 + scol]) = cvt4(bv);
    }
    __syncthreads();
#pragma unroll
    for (int kk = 0; kk < 64; kk += 32) {
      const int co = kk + (fq << 3);
      bf16x8 af[4], bfv[4];
#pragma unroll
      for (int m = 0; m < 4; ++m)
        af[m] = *reinterpret_cast<const bf16x8*>(&As[(wr + (m << 4) + fr) * 72 + co]);
#pragma unroll
      for (int n = 0; n < 4; ++n)
        bfv[n] = *reinterpret_cast<const bf16x8*>(&Bs[(wc + (n << 4) + fr) * 72 + co]);
#pragma unroll
      for (int m = 0; m < 4; ++m)
#pragma unroll
        for (int n = 0; n < 4; ++n)
          acc[m][n] = __builtin_amdgcn_mfma_f32_16x16x32_bf16(af[m], bfv[n], acc[m][n], 0, 0, 0);
    }
    __syncthreads();
  }

  // epilogue: retrieved + diff16 + loss/colv partials (plain stores only)
  float lsum = 0.f;
  float vcs[4] = {0.f, 0.f, 0.f, 0.f};
#pragma unroll
  for (int m = 0; m < 4; ++m) {
#pragma unroll
    for (int n = 0; n < 4; ++n) {
#pragma unroll
      for (int i = 0; i < 4; ++i) {
        const int gr = row0 + wr + (m << 4) + (fq << 2) + i;
        const int gc = vd0 + wc + (n << 4) + fr;
        const size_t oi = (size_t)gr * 512 + gc;
        const float rv = acc[m][n][i];
        outp[oi] = rv;
        const float vv = Vp[oi];
        const float d = rv - vv;
        lsum += d * d;
        vcs[n] += vv;
        union { __bf16 b; unsigned short u; } cd; cd.b = (__bf16)d;
        diff16[oi] = cd.u;
      }
    }
  }
#pragma unroll
  for (int o = 32; o; o >>= 1) lsum += __shfl_xor(lsum, o);
  if (lane == 0) redl[wv] = lsum;
#pragma unroll
  for (int n = 0; n < 4; ++n) {
    vcs[n] += __shfl_xor(vcs[n], 16);
    vcs[n] += __shfl_xor(vcs[n], 32);
  }
  if (fq == 0) {
#pragma unroll
    for (int n = 0; n < 4; ++n)
      redc[(wv << 6) + (n << 4) + fr] = vcs[n];
  }
  __syncthreads();
  if (t < 128) {
    const int side = t >> 6, lc = t & 63;
    colv_part[(size_t)rt * 512 + vd0 + t] =
        redc[side * 64 + lc] + redc[(side + 2) * 64 + lc];
  }
  if (t == 0)
    loss_part[tile] = redl[0] + redl[1] + redl[2] + redl[3];
}

// ---------------------------------------------------------------------------
// K3: grad_part[kc&3] += diff^T @ k (split-K 32 chunks, XCD-grouped).
// vd0==0 blocks also accumulate colk partials (k16 values pass through regs).
// ---------------------------------------------------------------------------
__global__ __launch_bounds__(256) void k3_grad(
    const unsigned short* __restrict__ diff16,
    const unsigned short* __restrict__ k16,
    float* __restrict__ grad_part, float* __restrict__ colk_part)
{
  __shared__ __align__(16) unsigned short At[2][128][40];
  __shared__ __align__(16) unsigned short Bt[2][128][40];
  const int t = threadIdx.x;
  const int lane = t & 63;
  const int wv = t >> 6;
  const int b = blockIdx.x;
  const int x = b & 7;
  const int q = b >> 3;
  const int tile = q & 15;
  const int kc = ((q >> 4) << 3) | x;       // all 16 tiles of kc share an XCD
  const int vd0 = (tile & 3) << 7;
  const int kd0 = (tile >> 2) << 7;
  const size_t r0 = (size_t)kc << 10;

  f32x4 acc[4][4];
#pragma unroll
  for (int m = 0; m < 4; ++m)
#pragma unroll
    for (int n = 0; n < 4; ++n)
      acc[m][n] = (f32x4){0.f, 0.f, 0.f, 0.f};

  float ck[16];
#pragma unroll
  for (int j = 0; j < 16; ++j) ck[j] = 0.f;

  const int dr = t >> 3;
  const int c0 = (t & 7) << 4;
  const int wr = (wv >> 1) << 6;
  const int wc = (wv & 1) << 6;
  const int fr = lane & 15;
  const int fq = lane >> 4;

  int cur = 0;
  for (int rr = 0; rr < 1024; rr += 32) {
    const size_t rowoff = (r0 + rr + dr) << 9;
    const ushort8_t a0 = *reinterpret_cast<const ushort8_t*>(&diff16[rowoff + vd0 + c0]);
    const ushort8_t a1 = *reinterpret_cast<const ushort8_t*>(&diff16[rowoff + vd0 + c0 + 8]);
    const ushort8_t b0 = *reinterpret_cast<const ushort8_t*>(&k16[rowoff + kd0 + c0]);
    const ushort8_t b1 = *reinterpret_cast<const ushort8_t*>(&k16[rowoff + kd0 + c0 + 8]);
    if (vd0 == 0) {
#pragma unroll
      for (int j = 0; j < 8; ++j) { ck[j] += bf2f(b0[j]); ck[8 + j] += bf2f(b1[j]); }
    }
    const int swz = ((c0 >> 4) & 3) << 3;
#pragma unroll
    for (int j = 0; j < 8; ++j) {
      const int drs = dr ^ swz;
      At[cur][c0 + j][drs] = a0[j];
      At[cur][c0 + 8 + j][drs] = a1[j];
      Bt[cur][c0 + j][drs] = b0[j];
      Bt[cur][c0 + 8 + j][drs] = b1[j];
    }
    __syncthreads();
    bf16x8 af[4], bfv[4];
#pragma unroll
    for (int m = 0; m < 4; ++m) {
      const int rA = wr + (m << 4) + fr;
      af[m] = *reinterpret_cast<const bf16x8*>(&At[cur][rA][(fq ^ ((rA >> 4) & 3)) << 3]);
    }
#pragma unroll
    for (int n = 0; n < 4; ++n) {
      const int rB = wc + (n << 4) + fr;
      bfv[n] = *reinterpret_cast<const bf16x8*>(&Bt[cur][rB][(fq ^ ((rB >> 4) & 3)) << 3]);
    }
#pragma unroll
    for (int m = 0; m < 4; ++m)
#pragma unroll
      for (int n = 0; n < 4; ++n)
        acc[m][n] = __builtin_amdgcn_mfma_f32_16x16x32_bf16(af[m], bfv[n], acc[m][n], 0, 0, 0);
    cur ^= 1;
  }

  float* gslab = grad_part + (size_t)(kc & 3) * 262144;
#pragma unroll
  for (int m = 0; m < 4; ++m)
#pragma unroll
    for (int n = 0; n < 4; ++n)
#pragma unroll
      for (int i = 0; i < 4; ++i)
        atomicAdd(&gslab[(size_t)(vd0 + wr + (m << 4) + (fq << 2) + i) * 512
                         + kd0 + wc + (n << 4) + fr], acc[m][n][i]);

  // colk partials: reduce 8 dr-threads sharing c0 (lanes l, l^8,16,32)
  if (vd0 == 0) {
#pragma unroll
    for (int j = 0; j < 16; ++j) {
      ck[j] += __shfl_xor(ck[j], 8);
      ck[j] += __shfl_xor(ck[j], 16);
      ck[j] += __shfl_xor(ck[j], 32);
    }
    __syncthreads();
    float* cred = (float*)&At[0][0][0];   // reuse LDS (512 f32)
    if (lane < 8) {
#pragma unroll
      for (int j = 0; j < 16; ++j) cred[(wv << 7) + (lane << 4) + j] = ck[j];
    }
    __syncthreads();
    if (t < 128) {
      colk_part[(size_t)kc * 512 + kd0 + t] =
          cred[t] + cred[128 + t] + cred[256 + t] + cred[384 + t];
    }
  }
}

// ---------------------------------------------------------------------------
// c1: reduce colk/colv/loss partials + gates (1 block); zeroes norm accums.
// ---------------------------------------------------------------------------
__global__ __launch_bounds__(256) void c1_gates(
    const float* __restrict__ gw, const float* __restrict__ gb,
    const float* __restrict__ ckp, const float* __restrict__ cvp,
    const float* __restrict__ lossp, float* __restrict__ scal,
    float* __restrict__ outp)
{
  __shared__ float ck[512], cv[512];
  __shared__ float red3[3][4];
  __shared__ float redl[4];
  const int t = threadIdx.x, lane = t & 63, wvi = t >> 6;

  for (int c = t; c < 512; c += 256) {
    float s = 0.f;
    for (int p = 0; p < 32; ++p) s += ckp[(size_t)p * 512 + c];
    ck[c] = s;
    float s2 = 0.f;
    for (int p = 0; p < 256; ++p) s2 += cvp[(size_t)p * 512 + c];
    cv[c] = s2;
  }
  float ls = lossp[t] + lossp[256 + t] + lossp[512 + t] + lossp[768 + t];
#pragma unroll
  for (int o = 32; o; o >>= 1) ls += __shfl_xor(ls, o);
  if (lane == 0) redl[wvi] = ls;
  __syncthreads();

  float p3[3] = {0.f, 0.f, 0.f};
  for (int j = t; j < 1024; j += 256) {
    const float kv = (j < 512 ? ck[j] : cv[j - 512]) * (1.0f / 32768.0f);
    p3[0] += kv * gw[j];
    p3[1] += kv * gw[1024 + j];
    p3[2] += kv * gw[2048 + j];
  }
#pragma unroll
  for (int o = 32; o; o >>= 1) {
#pragma unroll
    for (int g = 0; g < 3; ++g) p3[g] += __shfl_xor(p3[g], o);
  }
  if (lane == 0) { red3[0][wvi] = p3[0]; red3[1][wvi] = p3[1]; red3[2][wvi] = p3[2]; }
  __syncthreads();
  if (t == 0) {
    const float s0 = red3[0][0] + red3[0][1] + red3[0][2] + red3[0][3] + gb[0];
    const float s1 = red3[1][0] + red3[1][1] + red3[1][2] + red3[1][3] + gb[1];
    const float s2 = red3[2][0] + red3[2][1] + red3[2][2] + red3[2][3] + gb[2];
    const float alpha = 1.0f / (1.0f + expf(-s0));
    const float eta   = 1.0f / (1.0f + expf(-s1));
    const float theta = 1.0f / (1.0f + expf(-s2));
    scal[1] = 0.f; scal[2] = 0.f;          // norm accumulators for c2/c3
    scal[3] = alpha; scal[4] = eta; scal[5] = theta;
    outp[OUT_LOSS] = (redl[0] + redl[1] + redl[2] + redl[3]) * (1.0f / 16777216.0f);
    outp[OUT_ALPHA]     = alpha;
    outp[OUT_ALPHA + 1] = eta;
    outp[OUT_ALPHA + 2] = theta;
  }
}

__device__ __forceinline__ void block_atomic_sumsq(float sq, float* target) {
  __shared__ float red[4];
#pragma unroll
  for (int o = 32; o; o >>= 1) sq += __shfl_xor(sq, o);
  if ((threadIdx.x & 63) == 0) red[threadIdx.x >> 6] = sq;
  __syncthreads();
  if (threadIdx.x == 0) atomicAdd(target, red[0] + red[1] + red[2] + red[3]);
}

// c2: m_raw = eta*S - 0.005*theta*clip(grad); ||m||^2. grad = sum of 4 slabs.
__global__ __launch_bounds__(256) void c2_mom(
    const float* __restrict__ grad_part, const float* __restrict__ S,
    float* scal, float* __restrict__ m_raw)
{
  const float eta = scal[4];
  const float cth = 0.005f * scal[5];
  const int i = ((blockIdx.x << 8) + threadIdx.x) << 2;
  float4_t g = *reinterpret_cast<const float4_t*>(&grad_part[i]);
  const float4_t g1 = *reinterpret_cast<const float4_t*>(&grad_part[262144 + i]);
  const float4_t g2 = *reinterpret_cast<const float4_t*>(&grad_part[524288 + i]);
  const float4_t g3 = *reinterpret_cast<const float4_t*>(&grad_part[786432 + i]);
  const float4_t s = *reinterpret_cast<const float4_t*>(&S[i]);
  float4_t m; float sq = 0.f;
#pragma unroll
  for (int j = 0; j < 4; ++j) {
    float gj = (g[j] + g1[j] + g2[j] + g3[j]) * (2.0f / 16777216.0f);
    gj = fminf(1.0f, fmaxf(-1.0f, gj));
    m[j] = eta * s[j] - cth * gj;
    sq += m[j] * m[j];
  }
  *reinterpret_cast<float4_t*>(&m_raw[i]) = m;
  block_atomic_sumsq(sq, &scal[1]);
}

// c3: clip momentum -> out; w_raw = (1-alpha)*W + m; ||w||^2
__global__ __launch_bounds__(256) void c3_wt(
    const float* __restrict__ m_raw, const float* __restrict__ memw,
    float* scal, float* __restrict__ w_raw, float* __restrict__ outp)
{
  const float nm = sqrtf(scal[1]);
  const float sm = nm > 5.0f ? 5.0f / (nm + 1e-8f) : 1.0f;
  const float oma = 1.0f - scal[3];
  const int i = ((blockIdx.x << 8) + threadIdx.x) << 2;
  const float4_t mr = *reinterpret_cast<const float4_t*>(&m_raw[i]);
  const float4_t wi = *reinterpret_cast<const float4_t*>(&memw[i]);
  float4_t w; float sq = 0.f;
#pragma unroll
  for (int j = 0; j < 4; ++j) {
    const float m = mr[j] * sm;
    outp[OUT_MOM + i + j] = m;
    w[j] = oma * wi[j] + m;
    sq += w[j] * w[j];
  }
  *reinterpret_cast<float4_t*>(&w_raw[i]) = w;
  block_atomic_sumsq(sq, &scal[2]);
}

// c4: clip weight -> out
__global__ __launch_bounds__(256) void c4_wt(
    const float* __restrict__ w_raw, const float* __restrict__ scal,
    float* __restrict__ outp)
{
  const float nw = sqrtf(scal[2]);
  const float sw = nw > 5.0f ? 5.0f / (nw + 1e-8f) : 1.0f;
  const int i = ((blockIdx.x << 8) + threadIdx.x) << 2;
  const float4_t w = *reinterpret_cast<const float4_t*>(&w_raw[i]);
#pragma unroll
  for (int j = 0; j < 4; ++j)
    outp[OUT_W + i + j] = w[j] * sw;
}

// ---------------------------------------------------------------------------
extern "C" void kernel_launch(void* const* d_in, const int* in_sizes, int n_in,
                              void* d_out, int out_size, void* d_ws, size_t ws_size,
                              hipStream_t stream)
{
  const float* Kp = (const float*)d_in[0];
  const float* Vp = (const float*)d_in[1];
  const float* Wp = (const float*)d_in[2];
  const float* GW = (const float*)d_in[3];
  const float* GB = (const float*)d_in[4];
  const float* Sp = (const float*)d_in[5];
  float* outp = (float*)d_out;
  char* ws = (char*)d_ws;

  float* grad_part       = (float*)(ws + OFF_GRAD);
  float* colk_part       = (float*)(ws + OFF_CKP);
  float* colv_part       = (float*)(ws + OFF_CVP);
  float* loss_part       = (float*)(ws + OFF_LOSSP);
  float* scal            = (float*)(ws + OFF_SCAL);
  unsigned short* k16    = (unsigned short*)(ws + OFF_K16);
  unsigned short* diff16 = (unsigned short*)(ws + OFF_DIFF);
  float* m_raw           = (float*)(ws + OFF_MRAW);
  float* w_raw           = (float*)(ws + OFF_WRAW);

  hipMemsetAsync(ws + OFF_GRAD, 0, 4194304, stream);   // grad_part slabs

  k2_gemm<<<1024, 256, 0, stream>>>(Kp, Wp, Vp, outp, k16, diff16, colv_part, loss_part);
  k3_grad<<<512, 256, 0, stream>>>(diff16, k16, grad_part, colk_part);
  c1_gates<<<1, 256, 0, stream>>>(GW, GB, colk_part, colv_part, loss_part, scal, outp);
  c2_mom<<<256, 256, 0, stream>>>(grad_part, Sp, scal, m_raw);
  c3_wt<<<256, 256, 0, stream>>>(m_raw, Wp, scal, w_raw, outp);
  c4_wt<<<256, 256, 0, stream>>>(w_raw, scal, outp);
}

// Round 4
// 185.169 us; speedup vs baseline: 1.1849x; 1.1849x over previous
//
#include <hip/hip_runtime.h>
#include <math.h>

// ---------------------------------------------------------------------------
// TitansMemoryModule fused update, MI355X (gfx950) — round 4
//   K1: f32->bf16 convert of K,W (streaming, pure)
//   K2: retrieved = k16 @ w16^T. BK=32 double-buffered single-barrier
//       prefetch loop (T3-minimum), global_load_lds w/ pre-swizzled source,
//       conflict-free swizzled ds_read. Fused epilogue: V, diff16,
//       loss/colv partials (plain stores).
//   K3: grad = diff^T @ k (split-K 32 chunks, XCD-grouped, fused colk).
//   c1a/c1b: partial reductions + gates; c2-c4: momentum/weight + norm clips.
// Output (flat f32): retrieved[16777216], loss, new_weight[262144],
//   new_momentum[262144], alpha, eta, theta
// ---------------------------------------------------------------------------

typedef __bf16 bf16x8 __attribute__((ext_vector_type(8)));
typedef float f32x4 __attribute__((ext_vector_type(4)));
typedef float float4_t __attribute__((ext_vector_type(4)));
typedef unsigned short ushort4_t __attribute__((ext_vector_type(4)));
typedef unsigned short ushort8_t __attribute__((ext_vector_type(8)));

#define OUT_LOSS   16777216
#define OUT_W      16777217
#define OUT_MOM    17039361
#define OUT_ALPHA  17301505

// ws layout (bytes), total 69,275,712 (< round-1's proven 70,262,784)
#define OFF_GRAD   0u           // grad accum [512][512] f32 = 1 MB [memset 0]
#define OFF_CKP    1048576u     // colk_part [32][512] f32 (from K3)
#define OFF_LOSSP  1114112u     // loss_part [1024] f32 (plain stores, K2)
#define OFF_SCAL   1118208u     // scal[16]: 1=||m||^2 2=||w||^2 3=a 4=e 5=t
#define OFF_W16    1118272u     // 512 KB bf16 W
#define OFF_CVP    1642560u     // colv_part [256][512] f32 (from K2)
#define OFF_K16    2166848u     // 32 MB bf16 K
#define OFF_DIFF   35721280u    // 32 MB bf16 diff
#define OFF_MRAW   OFF_K16      // m_raw aliases k16 (dead after K3)
#define OFF_WRAW   (OFF_K16 + 1048576u)

__device__ __forceinline__ ushort4_t cvt4(float4_t v) {
  union { __bf16 b; unsigned short u; } c0, c1, c2, c3;
  c0.b = (__bf16)v.x; c1.b = (__bf16)v.y; c2.b = (__bf16)v.z; c3.b = (__bf16)v.w;
  ushort4_t h; h.x = c0.u; h.y = c1.u; h.z = c2.u; h.w = c3.u;
  return h;
}

__device__ __forceinline__ float bf2f(unsigned short u) {
  return __uint_as_float(((unsigned int)u) << 16);
}

__device__ __forceinline__ void gload_lds16(const unsigned short* g, unsigned short* l) {
  __builtin_amdgcn_global_load_lds(
      (const __attribute__((address_space(1))) unsigned int*)g,
      (__attribute__((address_space(3))) unsigned int*)l, 16, 0, 0);
}

// ---------------------------------------------------------------------------
// K1: pure f32->bf16 convert. Blocks 0..1023: K (16384 floats each);
// 1024..1039: W. 256 threads x 8 iters x 8 floats, ushort8 stores.
// ---------------------------------------------------------------------------
__global__ __launch_bounds__(256) void k1_convert(
    const float* __restrict__ Kp, const float* __restrict__ Wp,
    unsigned short* __restrict__ k16, unsigned short* __restrict__ w16)
{
  const int b = blockIdx.x;
  const float* src = (b < 1024) ? Kp : Wp;
  unsigned short* dst = (b < 1024) ? k16 : w16;
  const size_t base = (size_t)(b < 1024 ? b : b - 1024) * 16384;
  const int t = threadIdx.x;
#pragma unroll
  for (int j = 0; j < 8; ++j) {
    const size_t off = base + (size_t)j * 2048 + ((size_t)t << 3);
    const float4_t v0 = *reinterpret_cast<const float4_t*>(&src[off]);
    const float4_t v1 = *reinterpret_cast<const float4_t*>(&src[off + 4]);
    const ushort4_t h0 = cvt4(v0), h1 = cvt4(v1);
    ushort8_t h;
    h[0] = h0.x; h[1] = h0.y; h[2] = h0.z; h[3] = h0.w;
    h[4] = h1.x; h[5] = h1.y; h[6] = h1.z; h[7] = h1.w;
    *reinterpret_cast<ushort8_t*>(&dst[off]) = h;
  }
}

// ---------------------------------------------------------------------------
// K2: retrieved = k16 @ w16^T. 128x128 tile, BK=32, 4 waves (2x2 of 64x64).
// Double-buffered LDS, ONE barrier per k-step: stage(next) issued before
// compute(cur), so L2 latency hides under ds_read+MFMA (T3-minimum).
// Swizzle: LDS slot q holds global col-block q ^ ((row>>1)&3) — staged by
// pre-swizzling the per-lane GLOBAL address (LDS dest stays linear, rule #21);
// ds_read uses slot fq ^ ((fr>>1)&3) -> <=2-way banks (free).
// ---------------------------------------------------------------------------
__global__ __launch_bounds__(256, 4) void k2_gemm(
    const unsigned short* __restrict__ k16, const unsigned short* __restrict__ w16,
    const float* __restrict__ Vp, float* __restrict__ outp,
    unsigned short* __restrict__ diff16,
    float* __restrict__ colv_part, float* __restrict__ loss_part)
{
  __shared__ __align__(16) unsigned short As[2][4096];   // [buf][128*32]
  __shared__ __align__(16) unsigned short Bs[2][4096];
  __shared__ float redc[256];
  __shared__ float redl[4];

  const int t = threadIdx.x, lane = t & 63, wv = t >> 6;
  // XCD-grouped swizzle: the 4 vd-siblings of a rowtile share one XCD's L2.
  const int tile = (blockIdx.x & 7) * 128 + (blockIdx.x >> 3);
  const int rt = tile >> 2, vt = tile & 3;
  const int row0 = rt << 7, vd0 = vt << 7;

  f32x4 acc[4][4];
#pragma unroll
  for (int m = 0; m < 4; ++m)
#pragma unroll
    for (int n = 0; n < 4; ++n)
      acc[m][n] = (f32x4){0.f, 0.f, 0.f, 0.f};

  // staging geometry: wave wv covers LDS rows [wv*32, wv*32+32) in 2 instrs
  // of 16 rows; lane l -> row +(l>>2), slot (l&3); global col-block
  // pre-swizzled: (l&3) ^ ((l>>3)&3).
  const int cb = (((lane & 3) ^ ((lane >> 3) & 3)) << 3);
  const int sr = (wv << 5) + (lane >> 2);
  const unsigned short* gA = k16 + (size_t)(row0 + sr) * 512 + cb;
  const unsigned short* gB = w16 + (size_t)(vd0 + sr) * 512 + cb;

  const int fr = lane & 15, fq = lane >> 4;
  const int wr = (wv >> 1) << 6, wc = (wv & 1) << 6;
  const int rsw = ((fq ^ ((fr >> 1) & 3)) << 3);   // swizzled read slot offset

#define K2_STAGE(buf, kk0) do {                                  \
    gload_lds16(gA + (kk0), &As[buf][wv << 10]);                 \
    gload_lds16(gA + (kk0) + 8192, &As[buf][(wv << 10) + 512]);  \
    gload_lds16(gB + (kk0), &Bs[buf][wv << 10]);                 \
    gload_lds16(gB + (kk0) + 8192, &Bs[buf][(wv << 10) + 512]);  \
  } while (0)

  K2_STAGE(0, 0);
  __syncthreads();
  int cur = 0;
  for (int s = 0; s < 16; ++s) {
    if (s < 15) {
      if (cur) K2_STAGE(0, (s + 1) << 5);
      else     K2_STAGE(1, (s + 1) << 5);
    }
    bf16x8 af[4], bfv[4];
#pragma unroll
    for (int m = 0; m < 4; ++m)
      af[m] = *reinterpret_cast<const bf16x8*>(&As[cur][((wr + (m << 4) + fr) << 5) + rsw]);
#pragma unroll
    for (int n = 0; n < 4; ++n)
      bfv[n] = *reinterpret_cast<const bf16x8*>(&Bs[cur][((wc + (n << 4) + fr) << 5) + rsw]);
#pragma unroll
    for (int m = 0; m < 4; ++m)
#pragma unroll
      for (int n = 0; n < 4; ++n)
        acc[m][n] = __builtin_amdgcn_mfma_f32_16x16x32_bf16(af[m], bfv[n], acc[m][n], 0, 0, 0);
    __syncthreads();   // drains stage(next) + this step's ds_reads
    cur ^= 1;
  }
#undef K2_STAGE

  // epilogue: retrieved + diff16 + loss/colv partials (plain stores only)
  float lsum = 0.f;
  float vcs[4] = {0.f, 0.f, 0.f, 0.f};
#pragma unroll
  for (int m = 0; m < 4; ++m) {
#pragma unroll
    for (int n = 0; n < 4; ++n) {
#pragma unroll
      for (int i = 0; i < 4; ++i) {
        const int gr = row0 + wr + (m << 4) + (fq << 2) + i;
        const int gc = vd0 + wc + (n << 4) + fr;
        const size_t oi = (size_t)gr * 512 + gc;
        const float rv = acc[m][n][i];
        outp[oi] = rv;
        const float vv = Vp[oi];
        const float d = rv - vv;
        lsum += d * d;
        vcs[n] += vv;
        union { __bf16 b; unsigned short u; } cd; cd.b = (__bf16)d;
        diff16[oi] = cd.u;
      }
    }
  }
#pragma unroll
  for (int o = 32; o; o >>= 1) lsum += __shfl_xor(lsum, o);
  if (lane == 0) redl[wv] = lsum;
#pragma unroll
  for (int n = 0; n < 4; ++n) {
    vcs[n] += __shfl_xor(vcs[n], 16);
    vcs[n] += __shfl_xor(vcs[n], 32);
  }
  if (fq == 0) {
#pragma unroll
    for (int n = 0; n < 4; ++n)
      redc[(wv << 6) + (n << 4) + fr] = vcs[n];
  }
  __syncthreads();
  if (t < 128) {
    const int side = t >> 6, lc = t & 63;
    colv_part[(size_t)rt * 512 + vd0 + t] =
        redc[side * 64 + lc] + redc[(side + 2) * 64 + lc];
  }
  if (t == 0)
    loss_part[tile] = redl[0] + redl[1] + redl[2] + redl[3];
}

// ---------------------------------------------------------------------------
// K3: grad += diff^T @ k (split-K 32 chunks, XCD-grouped, dbuf 1-barrier).
// vd0==0 blocks also produce colk partials (values pass through regs).
// ---------------------------------------------------------------------------
__global__ __launch_bounds__(256) void k3_grad(
    const unsigned short* __restrict__ diff16,
    const unsigned short* __restrict__ k16,
    float* __restrict__ grad, float* __restrict__ colk_part)
{
  __shared__ __align__(16) unsigned short At[2][128][40];
  __shared__ __align__(16) unsigned short Bt[2][128][40];
  const int t = threadIdx.x;
  const int lane = t & 63;
  const int wv = t >> 6;
  const int b = blockIdx.x;
  const int x = b & 7;
  const int q = b >> 3;
  const int tile = q & 15;
  const int kc = ((q >> 4) << 3) | x;       // all 16 tiles of kc share an XCD
  const int vd0 = (tile & 3) << 7;
  const int kd0 = (tile >> 2) << 7;
  const size_t r0 = (size_t)kc << 10;

  f32x4 acc[4][4];
#pragma unroll
  for (int m = 0; m < 4; ++m)
#pragma unroll
    for (int n = 0; n < 4; ++n)
      acc[m][n] = (f32x4){0.f, 0.f, 0.f, 0.f};

  float ck[16];
#pragma unroll
  for (int j = 0; j < 16; ++j) ck[j] = 0.f;

  const int dr = t >> 3;
  const int c0 = (t & 7) << 4;
  const int wr = (wv >> 1) << 6;
  const int wc = (wv & 1) << 6;
  const int fr = lane & 15;
  const int fq = lane >> 4;

  int cur = 0;
  for (int rr = 0; rr < 1024; rr += 32) {
    const size_t rowoff = (r0 + rr + dr) << 9;
    const ushort8_t a0 = *reinterpret_cast<const ushort8_t*>(&diff16[rowoff + vd0 + c0]);
    const ushort8_t a1 = *reinterpret_cast<const ushort8_t*>(&diff16[rowoff + vd0 + c0 + 8]);
    const ushort8_t b0 = *reinterpret_cast<const ushort8_t*>(&k16[rowoff + kd0 + c0]);
    const ushort8_t b1 = *reinterpret_cast<const ushort8_t*>(&k16[rowoff + kd0 + c0 + 8]);
    if (vd0 == 0) {
#pragma unroll
      for (int j = 0; j < 8; ++j) { ck[j] += bf2f(b0[j]); ck[8 + j] += bf2f(b1[j]); }
    }
    const int swz = ((c0 >> 4) & 3) << 3;
#pragma unroll
    for (int j = 0; j < 8; ++j) {
      const int drs = dr ^ swz;
      At[cur][c0 + j][drs] = a0[j];
      At[cur][c0 + 8 + j][drs] = a1[j];
      Bt[cur][c0 + j][drs] = b0[j];
      Bt[cur][c0 + 8 + j][drs] = b1[j];
    }
    __syncthreads();
    bf16x8 af[4], bfv[4];
#pragma unroll
    for (int m = 0; m < 4; ++m) {
      const int rA = wr + (m << 4) + fr;
      af[m] = *reinterpret_cast<const bf16x8*>(&At[cur][rA][(fq ^ ((rA >> 4) & 3)) << 3]);
    }
#pragma unroll
    for (int n = 0; n < 4; ++n) {
      const int rB = wc + (n << 4) + fr;
      bfv[n] = *reinterpret_cast<const bf16x8*>(&Bt[cur][rB][(fq ^ ((rB >> 4) & 3)) << 3]);
    }
#pragma unroll
    for (int m = 0; m < 4; ++m)
#pragma unroll
      for (int n = 0; n < 4; ++n)
        acc[m][n] = __builtin_amdgcn_mfma_f32_16x16x32_bf16(af[m], bfv[n], acc[m][n], 0, 0, 0);
    cur ^= 1;
  }

#pragma unroll
  for (int m = 0; m < 4; ++m)
#pragma unroll
    for (int n = 0; n < 4; ++n)
#pragma unroll
      for (int i = 0; i < 4; ++i)
        atomicAdd(&grad[(size_t)(vd0 + wr + (m << 4) + (fq << 2) + i) * 512
                        + kd0 + wc + (n << 4) + fr], acc[m][n][i]);

  if (vd0 == 0) {
#pragma unroll
    for (int j = 0; j < 16; ++j) {
      ck[j] += __shfl_xor(ck[j], 8);
      ck[j] += __shfl_xor(ck[j], 16);
      ck[j] += __shfl_xor(ck[j], 32);
    }
    __syncthreads();
    float* cred = (float*)&At[0][0][0];   // reuse LDS (512 f32)
    if (lane < 8) {
#pragma unroll
      for (int j = 0; j < 16; ++j) cred[(wv << 7) + (lane << 4) + j] = ck[j];
    }
    __syncthreads();
    if (t < 128) {
      colk_part[(size_t)kc * 512 + kd0 + t] =
          cred[t] + cred[128 + t] + cred[256 + t] + cred[384 + t];
    }
  }
}

// ---------------------------------------------------------------------------
// c1a: reduce colk partials (32) and colv partials (256) -> colk/colv[512]
// ---------------------------------------------------------------------------
__global__ __launch_bounds__(256) void c1a_redcols(
    const float* __restrict__ ckp, const float* __restrict__ cvp,
    float* __restrict__ colk, float* __restrict__ colv)
{
  __shared__ float red[8][32];
  const int t = threadIdx.x, b = blockIdx.x;
  const int mtx = b >> 4;
  const int c = ((b & 15) << 5) + (t & 31);
  const int pg = t >> 5;
  const float* src = mtx ? cvp : ckp;
  const int P = mtx ? 256 : 32;
  float s = 0.f;
  for (int p = pg; p < P; p += 8) s += src[(size_t)p * 512 + c];
  red[pg][t & 31] = s;
  __syncthreads();
  if (pg == 0) {
    float tot = 0.f;
#pragma unroll
    for (int j = 0; j < 8; ++j) tot += red[j][t & 31];
    (mtx ? colv : colk)[c] = tot;
  }
}

// ---------------------------------------------------------------------------
// c1b: gates + loss finalize (1 block); zeroes norm accumulators.
// ---------------------------------------------------------------------------
__global__ __launch_bounds__(256) void c1b_gates(
    const float* __restrict__ gw, const float* __restrict__ gb,
    const float* __restrict__ colk, const float* __restrict__ colv,
    const float* __restrict__ lossp, float* __restrict__ scal,
    float* __restrict__ outp)
{
  __shared__ float red3[3][4];
  __shared__ float redl[4];
  const int t = threadIdx.x, lane = t & 63, wvi = t >> 6;
  float p3[3] = {0.f, 0.f, 0.f};
  for (int j = t; j < 1024; j += 256) {
    const float kv = (j < 512 ? colk[j] : colv[j - 512]) * (1.0f / 32768.0f);
    p3[0] += kv * gw[j];
    p3[1] += kv * gw[1024 + j];
    p3[2] += kv * gw[2048 + j];
  }
  float ls = lossp[t] + lossp[256 + t] + lossp[512 + t] + lossp[768 + t];
#pragma unroll
  for (int o = 32; o; o >>= 1) {
    ls += __shfl_xor(ls, o);
#pragma unroll
    for (int g = 0; g < 3; ++g) p3[g] += __shfl_xor(p3[g], o);
  }
  if (lane == 0) {
    red3[0][wvi] = p3[0]; red3[1][wvi] = p3[1]; red3[2][wvi] = p3[2];
    redl[wvi] = ls;
  }
  __syncthreads();
  if (t == 0) {
    const float s0 = red3[0][0] + red3[0][1] + red3[0][2] + red3[0][3] + gb[0];
    const float s1 = red3[1][0] + red3[1][1] + red3[1][2] + red3[1][3] + gb[1];
    const float s2 = red3[2][0] + red3[2][1] + red3[2][2] + red3[2][3] + gb[2];
    const float alpha = 1.0f / (1.0f + expf(-s0));
    const float eta   = 1.0f / (1.0f + expf(-s1));
    const float theta = 1.0f / (1.0f + expf(-s2));
    scal[1] = 0.f; scal[2] = 0.f;
    scal[3] = alpha; scal[4] = eta; scal[5] = theta;
    outp[OUT_LOSS] = (redl[0] + redl[1] + redl[2] + redl[3]) * (1.0f / 16777216.0f);
    outp[OUT_ALPHA]     = alpha;
    outp[OUT_ALPHA + 1] = eta;
    outp[OUT_ALPHA + 2] = theta;
  }
}

__device__ __forceinline__ void block_atomic_sumsq(float sq, float* target) {
  __shared__ float red[4];
#pragma unroll
  for (int o = 32; o; o >>= 1) sq += __shfl_xor(sq, o);
  if ((threadIdx.x & 63) == 0) red[threadIdx.x >> 6] = sq;
  __syncthreads();
  if (threadIdx.x == 0) atomicAdd(target, red[0] + red[1] + red[2] + red[3]);
}

// c2: m_raw = eta*S - 0.005*theta*clip(grad); accumulate ||m||^2
__global__ __launch_bounds__(256) void c2_mom(
    const float* __restrict__ grad, const float* __restrict__ S,
    float* scal, float* __restrict__ m_raw)
{
  const float eta = scal[4];
  const float cth = 0.005f * scal[5];
  const int i = ((blockIdx.x << 8) + threadIdx.x) << 2;
  const float4_t g = *reinterpret_cast<const float4_t*>(&grad[i]);
  const float4_t s = *reinterpret_cast<const float4_t*>(&S[i]);
  float4_t m; float sq = 0.f;
#pragma unroll
  for (int j = 0; j < 4; ++j) {
    float gj = g[j] * (2.0f / 16777216.0f);
    gj = fminf(1.0f, fmaxf(-1.0f, gj));
    m[j] = eta * s[j] - cth * gj;
    sq += m[j] * m[j];
  }
  *reinterpret_cast<float4_t*>(&m_raw[i]) = m;
  block_atomic_sumsq(sq, &scal[1]);
}

// c3: clip momentum -> out; w_raw = (1-alpha)*W + m; accumulate ||w||^2
__global__ __launch_bounds__(256) void c3_wt(
    const float* __restrict__ m_raw, const float* __restrict__ memw,
    float* scal, float* __restrict__ w_raw, float* __restrict__ outp)
{
  const float nm = sqrtf(scal[1]);
  const float sm = nm > 5.0f ? 5.0f / (nm + 1e-8f) : 1.0f;
  const float oma = 1.0f - scal[3];
  const int i = ((blockIdx.x << 8) + threadIdx.x) << 2;
  const float4_t mr = *reinterpret_cast<const float4_t*>(&m_raw[i]);
  const float4_t wi = *reinterpret_cast<const float4_t*>(&memw[i]);
  float4_t w; float sq = 0.f;
#pragma unroll
  for (int j = 0; j < 4; ++j) {
    const float m = mr[j] * sm;
    outp[OUT_MOM + i + j] = m;
    w[j] = oma * wi[j] + m;
    sq += w[j] * w[j];
  }
  *reinterpret_cast<float4_t*>(&w_raw[i]) = w;
  block_atomic_sumsq(sq, &scal[2]);
}

// c4: clip weight -> out
__global__ __launch_bounds__(256) void c4_wt(
    const float* __restrict__ w_raw, const float* __restrict__ scal,
    float* __restrict__ outp)
{
  const float nw = sqrtf(scal[2]);
  const float sw = nw > 5.0f ? 5.0f / (nw + 1e-8f) : 1.0f;
  const int i = ((blockIdx.x << 8) + threadIdx.x) << 2;
  const float4_t w = *reinterpret_cast<const float4_t*>(&w_raw[i]);
#pragma unroll
  for (int j = 0; j < 4; ++j)
    outp[OUT_W + i + j] = w[j] * sw;
}

// ---------------------------------------------------------------------------
extern "C" void kernel_launch(void* const* d_in, const int* in_sizes, int n_in,
                              void* d_out, int out_size, void* d_ws, size_t ws_size,
                              hipStream_t stream)
{
  const float* Kp = (const float*)d_in[0];
  const float* Vp = (const float*)d_in[1];
  const float* Wp = (const float*)d_in[2];
  const float* GW = (const float*)d_in[3];
  const float* GB = (const float*)d_in[4];
  const float* Sp = (const float*)d_in[5];
  float* outp = (float*)d_out;
  char* ws = (char*)d_ws;

  float* grad            = (float*)(ws + OFF_GRAD);
  float* colk_part       = (float*)(ws + OFF_CKP);
  float* loss_part       = (float*)(ws + OFF_LOSSP);
  float* scal            = (float*)(ws + OFF_SCAL);
  unsigned short* w16    = (unsigned short*)(ws + OFF_W16);
  float* colv_part       = (float*)(ws + OFF_CVP);
  unsigned short* k16    = (unsigned short*)(ws + OFF_K16);
  unsigned short* diff16 = (unsigned short*)(ws + OFF_DIFF);
  float* m_raw           = (float*)(ws + OFF_MRAW);
  float* w_raw           = (float*)(ws + OFF_WRAW);
  float* colk            = scal + 16;          // reuse scal page: 512 f32
  float* colv            = scal + 16 + 512;    // within OFF_SCAL..OFF_W16? no —
  // scal page is only 64 B; place colk/colv at end of colk_part region instead
  colk = colk_part + 32 * 512;                 // unused tail? CKP is exactly 32*512
  // -> carve from loss_part page (4 KB = 1024 f32): lossp uses 1024... use CVP tail:
  colk = colv_part + 256 * 512 - 1024;         // last 1024 f32 of CVP unused? no.
  // Clean solution: put colk/colv in grad page tail? grad is exactly 1 MB used.
  // Use dedicated slots: reuse w_raw page (only live c3->c4) is unsafe pre-c1.
  // Simplest: alias the LAST 4 KB of DIFF region (diff16 is dead after K3,
  // c1a runs after K3): 1024 floats at end of diff region.
  colk = (float*)(ws + OFF_DIFF + 33554432u - 4096u);
  colv = colk + 512;

  hipMemsetAsync(ws + OFF_GRAD, 0, 1048576, stream);

  k1_convert<<<1040, 256, 0, stream>>>(Kp, Wp, k16, w16);
  k2_gemm<<<1024, 256, 0, stream>>>(k16, w16, Vp, outp, diff16, colv_part, loss_part);
  k3_grad<<<512, 256, 0, stream>>>(diff16, k16, grad, colk_part);
  c1a_redcols<<<32, 256, 0, stream>>>(colk_part, colv_part, colk, colv);
  c1b_gates<<<1, 256, 0, stream>>>(GW, GB, colk, colv, loss_part, scal, outp);
  c2_mom<<<256, 256, 0, stream>>>(grad, Sp, scal, m_raw);
  c3_wt<<<256, 256, 0, stream>>>(m_raw, Wp, scal, w_raw, outp);
  c4_wt<<<256, 256, 0, stream>>>(w_raw, scal, outp);
}

// Round 6
// 173.598 us; speedup vs baseline: 1.2639x; 1.0667x over previous
//
#include <hip/hip_runtime.h>
#include <math.h>

// ---------------------------------------------------------------------------
// TitansMemoryModule fused update, MI355X (gfx950) — round 6
//   All components are round-2-proven; single structural change: K2 tile
//   128x128 -> 128x64 (24 KB LDS, 6 blocks/CU, 2048 blocks) for TLP.
//   K1: f32->bf16 convert of K,W + colk partials (128-row blocks)
//   K2: retrieved = k16 @ w16^T, BK=64 single-buffer global_load_lds,
//       linear LDS, fused epilogue (V, diff16, loss/colv partials)
//   K3: grad = diff^T @ k (round-2 verbatim: split-K 32, XCD-grouped)
//   c1a/c1b: reductions + gates; c2-c4: momentum/weight + norm clips
// Output (flat f32): retrieved[16777216], loss, new_weight[262144],
//   new_momentum[262144], alpha, eta, theta
// ---------------------------------------------------------------------------

typedef __bf16 bf16x8 __attribute__((ext_vector_type(8)));
typedef float f32x4 __attribute__((ext_vector_type(4)));
typedef float float4_t __attribute__((ext_vector_type(4)));
typedef unsigned short ushort4_t __attribute__((ext_vector_type(4)));
typedef unsigned short ushort8_t __attribute__((ext_vector_type(8)));

#define OUT_LOSS   16777216
#define OUT_W      16777217
#define OUT_MOM    17039361
#define OUT_ALPHA  17301505

// ws layout (bytes), total 69,742,656 (< round-2's proven 70,259,776)
#define OFF_GRAD   0u           // grad accum [512][512] f32 = 1 MB [memset 0]
#define OFF_CKP    1048576u     // colk_part [256][512] f32 = 512 KB (K1)
#define OFF_CVP    1572864u     // colv_part [256][512] f32 = 512 KB (K2)
#define OFF_LOSSP  2097152u     // loss_part [2048] f32 = 8 KB (K2)
#define OFF_COLK   2105344u     // colk [512] f32
#define OFF_COLV   2107392u     // colv [512] f32
#define OFF_SCAL   2109440u     // scal[16]: 1=||m||^2 2=||w||^2 3=a 4=e 5=t
#define OFF_W16    2109504u     // 512 KB bf16 W
#define OFF_K16    2633792u     // 32 MB bf16 K (row-major)
#define OFF_DIFF   36188224u    // 32 MB bf16 diff (row-major)
#define OFF_MRAW   OFF_K16      // m_raw aliases k16 (dead after K3)
#define OFF_WRAW   (OFF_K16 + 1048576u)

__device__ __forceinline__ ushort4_t cvt4(float4_t v) {
  union { __bf16 b; unsigned short u; } c0, c1, c2, c3;
  c0.b = (__bf16)v.x; c1.b = (__bf16)v.y; c2.b = (__bf16)v.z; c3.b = (__bf16)v.w;
  ushort4_t h; h.x = c0.u; h.y = c1.u; h.z = c2.u; h.w = c3.u;
  return h;
}

__device__ __forceinline__ void gload_lds16(const unsigned short* g, unsigned short* l) {
  __builtin_amdgcn_global_load_lds(
      (const __attribute__((address_space(1))) unsigned int*)g,
      (__attribute__((address_space(3))) unsigned int*)l, 16, 0, 0);
}

// ---------------------------------------------------------------------------
// K1: convert K (bid<256, 128 rows each) and W (bid 256..271, 32 rows each)
// to bf16; per-block column-sum partials for K (no atomics).
// ---------------------------------------------------------------------------
__global__ __launch_bounds__(256) void k1_convert(
    const float* __restrict__ Kp, const float* __restrict__ Wp,
    unsigned short* __restrict__ k16, unsigned short* __restrict__ w16,
    float* __restrict__ colk_part)
{
  __shared__ float cp[512];
  const int t = threadIdx.x;
  const int cg = t & 127;          // column group of 4
  const int g = t >> 7;            // row-phase 0/1
  const int b = blockIdx.x;
  if (b < 256) {
    const int r0 = b << 7;
    float p0 = 0.f, p1 = 0.f, p2 = 0.f, p3 = 0.f;
#pragma unroll 4
    for (int rr = g; rr < 128; rr += 2) {
      const size_t off = (size_t)(r0 + rr) * 512 + (cg << 2);
      const float4_t v = *reinterpret_cast<const float4_t*>(&Kp[off]);
      *reinterpret_cast<ushort4_t*>(&k16[off]) = cvt4(v);
      p0 += v.x; p1 += v.y; p2 += v.z; p3 += v.w;
    }
    if (g == 1) {
      cp[(cg << 2) + 0] = p0; cp[(cg << 2) + 1] = p1;
      cp[(cg << 2) + 2] = p2; cp[(cg << 2) + 3] = p3;
    }
    __syncthreads();
    if (g == 0) {
      colk_part[(size_t)b * 512 + (cg << 2) + 0] = p0 + cp[(cg << 2) + 0];
      colk_part[(size_t)b * 512 + (cg << 2) + 1] = p1 + cp[(cg << 2) + 1];
      colk_part[(size_t)b * 512 + (cg << 2) + 2] = p2 + cp[(cg << 2) + 2];
      colk_part[(size_t)b * 512 + (cg << 2) + 3] = p3 + cp[(cg << 2) + 3];
    }
  } else {
    const int r0 = (b - 256) << 5;
#pragma unroll 4
    for (int rr = g; rr < 32; rr += 2) {
      const size_t off = (size_t)(r0 + rr) * 512 + (cg << 2);
      const float4_t v = *reinterpret_cast<const float4_t*>(&Wp[off]);
      *reinterpret_cast<ushort4_t*>(&w16[off]) = cvt4(v);
    }
  }
}

// ---------------------------------------------------------------------------
// K2: retrieved = k16 @ w16^T.  128x64 tile, BK=64, single-buffer,
// global_load_lds(16B), linear LDS (round-2 proven core).
// 4 waves as 2x2 of 64x32. 24 KB LDS -> 6 blocks/CU. 2048 blocks,
// XCD-grouped so the 8 vd-siblings of a rowtile share one XCD's L2.
// Fused epilogue: V read, diff16 write, loss/colv partials (plain stores).
// ---------------------------------------------------------------------------
__global__ __launch_bounds__(256) void k2_gemm(
    const unsigned short* __restrict__ k16, const unsigned short* __restrict__ w16,
    const float* __restrict__ Vp, float* __restrict__ outp,
    unsigned short* __restrict__ diff16,
    float* __restrict__ colv_part, float* __restrict__ loss_part)
{
  __shared__ __align__(16) unsigned short As[8192];   // [128][64] bf16, linear
  __shared__ __align__(16) unsigned short Bs[4096];   // [64][64]  bf16, linear
  __shared__ float redc[128];
  __shared__ float redl[4];

  const int t = threadIdx.x, lane = t & 63, wv = t >> 6;
  const int tile = (blockIdx.x & 7) * 256 + (blockIdx.x >> 3);  // XCD-grouped
  const int rt = tile >> 3, vt = tile & 7;
  const int row0 = rt << 7, vd0 = vt << 6;

  f32x4 acc[4][2];
#pragma unroll
  for (int m = 0; m < 4; ++m)
#pragma unroll
    for (int n = 0; n < 2; ++n)
      acc[m][n] = (f32x4){0.f, 0.f, 0.f, 0.f};

  // staging: wave wv, instr i covers rows i*32 + wv*8 + (lane>>3), 16B/lane
  const int srow = (wv << 3) + (lane >> 3);
  const int scol = (lane & 7) << 3;
  const unsigned short* pA = k16 + (size_t)(row0 + srow) * 512 + scol;
  const unsigned short* pB = w16 + (size_t)(vd0 + srow) * 512 + scol;
  unsigned short* lA = &As[wv << 9];
  unsigned short* lB = &Bs[wv << 9];

  const int fr = lane & 15, fq = lane >> 4;
  const int wr = (wv >> 1) << 6, wc = (wv & 1) << 5;

  for (int kk0 = 0; kk0 < 512; kk0 += 64) {
#pragma unroll
    for (int i = 0; i < 4; ++i)
      gload_lds16(pA + (i << 14) + kk0, lA + (i << 11));   // i*32 rows
#pragma unroll
    for (int i = 0; i < 2; ++i)
      gload_lds16(pB + (i << 14) + kk0, lB + (i << 11));
    __syncthreads();
#pragma unroll
    for (int kk = 0; kk < 64; kk += 32) {
      const int co = kk + (fq << 3);
      bf16x8 af[4], bfv[2];
#pragma unroll
      for (int m = 0; m < 4; ++m)
        af[m] = *reinterpret_cast<const bf16x8*>(&As[((wr + (m << 4) + fr) << 6) + co]);
#pragma unroll
      for (int n = 0; n < 2; ++n)
        bfv[n] = *reinterpret_cast<const bf16x8*>(&Bs[((wc + (n << 4) + fr) << 6) + co]);
#pragma unroll
      for (int m = 0; m < 4; ++m)
#pragma unroll
        for (int n = 0; n < 2; ++n)
          acc[m][n] = __builtin_amdgcn_mfma_f32_16x16x32_bf16(af[m], bfv[n], acc[m][n], 0, 0, 0);
    }
    __syncthreads();
  }

  // epilogue: retrieved + diff16 + loss/colv partials (plain stores only)
  float lsum = 0.f;
  float vcs[2] = {0.f, 0.f};
#pragma unroll
  for (int m = 0; m < 4; ++m) {
#pragma unroll
    for (int n = 0; n < 2; ++n) {
#pragma unroll
      for (int i = 0; i < 4; ++i) {
        const int rl = wr + (m << 4) + (fq << 2) + i;   // 0..127
        const int cl = wc + (n << 4) + fr;              // 0..63
        const size_t oi = (size_t)(row0 + rl) * 512 + vd0 + cl;
        const float rv = acc[m][n][i];
        outp[oi] = rv;
        const float vv = Vp[oi];
        const float d = rv - vv;
        lsum += d * d;
        vcs[n] += vv;
        union { __bf16 b; unsigned short u; } cd; cd.b = (__bf16)d;
        diff16[oi] = cd.u;
      }
    }
  }
#pragma unroll
  for (int o = 32; o; o >>= 1) lsum += __shfl_xor(lsum, o);
  if (lane == 0) redl[wv] = lsum;
#pragma unroll
  for (int n = 0; n < 2; ++n) {
    vcs[n] += __shfl_xor(vcs[n], 16);
    vcs[n] += __shfl_xor(vcs[n], 32);
  }
  if (fq == 0) {
#pragma unroll
    for (int n = 0; n < 2; ++n)
      redc[(wv << 5) + (n << 4) + fr] = vcs[n];
  }
  __syncthreads();
  if (t < 64) {   // column t of this block's 64-col slab
    const int h = t >> 5, lc = t & 31;
    colv_part[(size_t)rt * 512 + vd0 + t] =
        redc[(h << 5) + lc] + redc[((h + 2) << 5) + lc];
  }
  if (t == 0)
    loss_part[tile] = redl[0] + redl[1] + redl[2] + redl[3];
}

// ---------------------------------------------------------------------------
// K3: grad += diff^T @ k  (round-2 verbatim: split-K 32 chunks of 1024 rows,
// XCD-grouped, transposed LDS staging, f32 atomics).
// ---------------------------------------------------------------------------
__global__ __launch_bounds__(256) void k3_grad(
    const unsigned short* __restrict__ diff16,
    const unsigned short* __restrict__ k16,
    float* __restrict__ grad)
{
  __shared__ __align__(16) unsigned short At[2][128][40];
  __shared__ __align__(16) unsigned short Bt[2][128][40];
  const int t = threadIdx.x;
  const int lane = t & 63;
  const int wv = t >> 6;
  const int b = blockIdx.x;
  const int x = b & 7;
  const int q = b >> 3;
  const int tile = q & 15;
  const int kc = ((q >> 4) << 3) | x;
  const int vd0 = (tile & 3) << 7;
  const int kd0 = (tile >> 2) << 7;
  const size_t r0 = (size_t)kc << 10;

  f32x4 acc[4][4];
#pragma unroll
  for (int m = 0; m < 4; ++m)
#pragma unroll
    for (int n = 0; n < 4; ++n)
      acc[m][n] = (f32x4){0.f, 0.f, 0.f, 0.f};

  const int dr = t >> 3;
  const int c0 = (t & 7) << 4;
  const int wr = (wv >> 1) << 6;
  const int wc = (wv & 1) << 6;
  const int fr = lane & 15;
  const int fq = lane >> 4;

  int cur = 0;
  for (int rr = 0; rr < 1024; rr += 32) {
    const size_t rowoff = (r0 + rr + dr) << 9;
    const ushort8_t a0 = *reinterpret_cast<const ushort8_t*>(&diff16[rowoff + vd0 + c0]);
    const ushort8_t a1 = *reinterpret_cast<const ushort8_t*>(&diff16[rowoff + vd0 + c0 + 8]);
    const ushort8_t b0 = *reinterpret_cast<const ushort8_t*>(&k16[rowoff + kd0 + c0]);
    const ushort8_t b1 = *reinterpret_cast<const ushort8_t*>(&k16[rowoff + kd0 + c0 + 8]);
    const int swz = ((c0 >> 4) & 3) << 3;
#pragma unroll
    for (int j = 0; j < 8; ++j) {
      const int drs = dr ^ swz;
      At[cur][c0 + j][drs] = a0[j];
      At[cur][c0 + 8 + j][drs] = a1[j];
      Bt[cur][c0 + j][drs] = b0[j];
      Bt[cur][c0 + 8 + j][drs] = b1[j];
    }
    __syncthreads();
    bf16x8 af[4], bfv[4];
#pragma unroll
    for (int m = 0; m < 4; ++m) {
      const int rA = wr + (m << 4) + fr;
      af[m] = *reinterpret_cast<const bf16x8*>(&At[cur][rA][(fq ^ ((rA >> 4) & 3)) << 3]);
    }
#pragma unroll
    for (int n = 0; n < 4; ++n) {
      const int rB = wc + (n << 4) + fr;
      bfv[n] = *reinterpret_cast<const bf16x8*>(&Bt[cur][rB][(fq ^ ((rB >> 4) & 3)) << 3]);
    }
#pragma unroll
    for (int m = 0; m < 4; ++m)
#pragma unroll
      for (int n = 0; n < 4; ++n)
        acc[m][n] = __builtin_amdgcn_mfma_f32_16x16x32_bf16(af[m], bfv[n], acc[m][n], 0, 0, 0);
    cur ^= 1;
  }
#pragma unroll
  for (int m = 0; m < 4; ++m)
#pragma unroll
    for (int n = 0; n < 4; ++n)
#pragma unroll
      for (int i = 0; i < 4; ++i)
        atomicAdd(&grad[(size_t)(vd0 + wr + (m << 4) + (fq << 2) + i) * 512
                        + kd0 + wc + (n << 4) + fr], acc[m][n][i]);
}

// ---------------------------------------------------------------------------
// c1a: reduce colk partials (256) and colv partials (256) -> colk/colv[512]
// ---------------------------------------------------------------------------
__global__ __launch_bounds__(256) void c1a_redcols(
    const float* __restrict__ ckp, const float* __restrict__ cvp,
    float* __restrict__ colk, float* __restrict__ colv)
{
  __shared__ float red[8][32];
  const int t = threadIdx.x, b = blockIdx.x;
  const int mtx = b >> 4;
  const int c = ((b & 15) << 5) + (t & 31);
  const int pg = t >> 5;
  const float* src = mtx ? cvp : ckp;
  float s = 0.f;
  for (int p = pg; p < 256; p += 8) s += src[(size_t)p * 512 + c];
  red[pg][t & 31] = s;
  __syncthreads();
  if (pg == 0) {
    float tot = 0.f;
#pragma unroll
    for (int j = 0; j < 8; ++j) tot += red[j][t & 31];
    (mtx ? colv : colk)[c] = tot;
  }
}

// ---------------------------------------------------------------------------
// c1b: gates + loss finalize (1 block); zeroes norm accumulators.
// ---------------------------------------------------------------------------
__global__ __launch_bounds__(256) void c1b_gates(
    const float* __restrict__ gw, const float* __restrict__ gb,
    const float* __restrict__ colk, const float* __restrict__ colv,
    const float* __restrict__ lossp, float* __restrict__ scal,
    float* __restrict__ outp)
{
  __shared__ float red3[3][4];
  __shared__ float redl[4];
  const int t = threadIdx.x, lane = t & 63, wvi = t >> 6;
  float p3[3] = {0.f, 0.f, 0.f};
  for (int j = t; j < 1024; j += 256) {
    const float kv = (j < 512 ? colk[j] : colv[j - 512]) * (1.0f / 32768.0f);
    p3[0] += kv * gw[j];
    p3[1] += kv * gw[1024 + j];
    p3[2] += kv * gw[2048 + j];
  }
  float ls = 0.f;
#pragma unroll
  for (int q = 0; q < 8; ++q) ls += lossp[t + (q << 8)];
#pragma unroll
  for (int o = 32; o; o >>= 1) {
    ls += __shfl_xor(ls, o);
#pragma unroll
    for (int g = 0; g < 3; ++g) p3[g] += __shfl_xor(p3[g], o);
  }
  if (lane == 0) {
    red3[0][wvi] = p3[0]; red3[1][wvi] = p3[1]; red3[2][wvi] = p3[2];
    redl[wvi] = ls;
  }
  __syncthreads();
  if (t == 0) {
    const float s0 = red3[0][0] + red3[0][1] + red3[0][2] + red3[0][3] + gb[0];
    const float s1 = red3[1][0] + red3[1][1] + red3[1][2] + red3[1][3] + gb[1];
    const float s2 = red3[2][0] + red3[2][1] + red3[2][2] + red3[2][3] + gb[2];
    const float alpha = 1.0f / (1.0f + expf(-s0));
    const float eta   = 1.0f / (1.0f + expf(-s1));
    const float theta = 1.0f / (1.0f + expf(-s2));
    scal[1] = 0.f; scal[2] = 0.f;
    scal[3] = alpha; scal[4] = eta; scal[5] = theta;
    outp[OUT_LOSS] = (redl[0] + redl[1] + redl[2] + redl[3]) * (1.0f / 16777216.0f);
    outp[OUT_ALPHA]     = alpha;
    outp[OUT_ALPHA + 1] = eta;
    outp[OUT_ALPHA + 2] = theta;
  }
}

__device__ __forceinline__ void block_atomic_sumsq(float sq, float* target) {
  __shared__ float red[4];
#pragma unroll
  for (int o = 32; o; o >>= 1) sq += __shfl_xor(sq, o);
  if ((threadIdx.x & 63) == 0) red[threadIdx.x >> 6] = sq;
  __syncthreads();
  if (threadIdx.x == 0) atomicAdd(target, red[0] + red[1] + red[2] + red[3]);
}

// c2: m_raw = eta*S - 0.005*theta*clip(grad); accumulate ||m||^2
__global__ __launch_bounds__(256) void c2_mom(
    const float* __restrict__ grad, const float* __restrict__ S,
    float* scal, float* __restrict__ m_raw)
{
  const float eta = scal[4];
  const float cth = 0.005f * scal[5];
  const int i = ((blockIdx.x << 8) + threadIdx.x) << 2;
  const float4_t g = *reinterpret_cast<const float4_t*>(&grad[i]);
  const float4_t s = *reinterpret_cast<const float4_t*>(&S[i]);
  float4_t m; float sq = 0.f;
#pragma unroll
  for (int j = 0; j < 4; ++j) {
    float gj = g[j] * (2.0f / 16777216.0f);
    gj = fminf(1.0f, fmaxf(-1.0f, gj));
    m[j] = eta * s[j] - cth * gj;
    sq += m[j] * m[j];
  }
  *reinterpret_cast<float4_t*>(&m_raw[i]) = m;
  block_atomic_sumsq(sq, &scal[1]);
}

// c3: clip momentum -> out; w_raw = (1-alpha)*W + m; accumulate ||w||^2
__global__ __launch_bounds__(256) void c3_wt(
    const float* __restrict__ m_raw, const float* __restrict__ memw,
    float* scal, float* __restrict__ w_raw, float* __restrict__ outp)
{
  const float nm = sqrtf(scal[1]);
  const float sm = nm > 5.0f ? 5.0f / (nm + 1e-8f) : 1.0f;
  const float oma = 1.0f - scal[3];
  const int i = ((blockIdx.x << 8) + threadIdx.x) << 2;
  const float4_t mr = *reinterpret_cast<const float4_t*>(&m_raw[i]);
  const float4_t wi = *reinterpret_cast<const float4_t*>(&memw[i]);
  float4_t w; float sq = 0.f;
#pragma unroll
  for (int j = 0; j < 4; ++j) {
    const float m = mr[j] * sm;
    outp[OUT_MOM + i + j] = m;
    w[j] = oma * wi[j] + m;
    sq += w[j] * w[j];
  }
  *reinterpret_cast<float4_t*>(&w_raw[i]) = w;
  block_atomic_sumsq(sq, &scal[2]);
}

// c4: clip weight -> out
__global__ __launch_bounds__(256) void c4_wt(
    const float* __restrict__ w_raw, const float* __restrict__ scal,
    float* __restrict__ outp)
{
  const float nw = sqrtf(scal[2]);
  const float sw = nw > 5.0f ? 5.0f / (nw + 1e-8f) : 1.0f;
  const int i = ((blockIdx.x << 8) + threadIdx.x) << 2;
  const float4_t w = *reinterpret_cast<const float4_t*>(&w_raw[i]);
#pragma unroll
  for (int j = 0; j < 4; ++j)
    outp[OUT_W + i + j] = w[j] * sw;
}

// ---------------------------------------------------------------------------
extern "C" void kernel_launch(void* const* d_in, const int* in_sizes, int n_in,
                              void* d_out, int out_size, void* d_ws, size_t ws_size,
                              hipStream_t stream)
{
  const float* Kp = (const float*)d_in[0];
  const float* Vp = (const float*)d_in[1];
  const float* Wp = (const float*)d_in[2];
  const float* GW = (const float*)d_in[3];
  const float* GB = (const float*)d_in[4];
  const float* Sp = (const float*)d_in[5];
  float* outp = (float*)d_out;
  char* ws = (char*)d_ws;

  float* grad            = (float*)(ws + OFF_GRAD);
  float* colk_part       = (float*)(ws + OFF_CKP);
  float* colv_part       = (float*)(ws + OFF_CVP);
  float* loss_part       = (float*)(ws + OFF_LOSSP);
  float* colk            = (float*)(ws + OFF_COLK);
  float* colv            = (float*)(ws + OFF_COLV);
  float* scal            = (float*)(ws + OFF_SCAL);
  unsigned short* w16    = (unsigned short*)(ws + OFF_W16);
  unsigned short* k16    = (unsigned short*)(ws + OFF_K16);
  unsigned short* diff16 = (unsigned short*)(ws + OFF_DIFF);
  float* m_raw           = (float*)(ws + OFF_MRAW);
  float* w_raw           = (float*)(ws + OFF_WRAW);

  hipMemsetAsync(ws + OFF_GRAD, 0, 1048576, stream);

  k1_convert<<<272, 256, 0, stream>>>(Kp, Wp, k16, w16, colk_part);
  k2_gemm<<<2048, 256, 0, stream>>>(k16, w16, Vp, outp, diff16, colv_part, loss_part);
  k3_grad<<<512, 256, 0, stream>>>(diff16, k16, grad);
  c1a_redcols<<<32, 256, 0, stream>>>(colk_part, colv_part, colk, colv);
  c1b_gates<<<1, 256, 0, stream>>>(GW, GB, colk, colv, loss_part, scal, outp);
  c2_mom<<<256, 256, 0, stream>>>(grad, Sp, scal, m_raw);
  c3_wt<<<256, 256, 0, stream>>>(m_raw, Wp, scal, w_raw, outp);
  c4_wt<<<256, 256, 0, stream>>>(w_raw, scal, outp);
}